// Round 4
// baseline (1509.562 us; speedup 1.0000x reference)
//
#include <hip/hip_runtime.h>
#include <math.h>

#define DEV_INLINE __device__ __forceinline__
typedef unsigned short ushort;
typedef __attribute__((ext_vector_type(8))) short bf16x8;
typedef __attribute__((ext_vector_type(4))) float f32x4;

DEV_INLINE float lrelu(float x){ return x > 0.f ? x : 0.2f*x; }
DEV_INLINE float eluf(float x){ return x>0.f? x : (__expf(x)-1.f); }
DEV_INLINE ushort f2bf(float f){
  unsigned u = __float_as_uint(f);
  return (ushort)((u + 0x7FFFu + ((u>>16)&1u)) >> 16);   // RNE
}
DEV_INLINE float b2f(ushort u){ return __uint_as_float(((unsigned)u)<<16); }

// ---------------- node GEMM: Cb[n][64] = bf16(A[n][K] @ W[K][64] (+bias)) ----------------
__global__ __launch_bounds__(256) void gemm_n64(const float* __restrict__ A, const float* __restrict__ W,
    const float* __restrict__ bias, ushort* __restrict__ Cb, int n, int K)
{
  int j = threadIdx.x & 63;
  int node = blockIdx.x*4 + (threadIdx.x>>6);
  if (node >= n) return;
  const float4* A4 = (const float4*)(A + (size_t)node*K);
  float acc = 0.f;
  int K4 = K>>2;
  for (int k4 = 0; k4 < K4; ++k4) {
    float4 a = A4[k4];
    const float* w = W + k4*256 + j;
    acc = fmaf(a.x, w[0],   acc);
    acc = fmaf(a.y, w[64],  acc);
    acc = fmaf(a.z, w[128], acc);
    acc = fmaf(a.w, w[192], acc);
  }
  if (bias) acc += bias[j];
  Cb[(size_t)node*64 + j] = f2bf(acc);
}

// ---------------- CSR build (grouped by dst) ----------------
__global__ __launch_bounds__(256) void hist_kernel(const int* __restrict__ dst, int* __restrict__ deg, int E)
{
  int e = blockIdx.x*blockDim.x + threadIdx.x;
  if (e < E) atomicAdd(deg + dst[e], 1);
}

__global__ __launch_bounds__(256) void scan_p1(const int* __restrict__ deg, int* __restrict__ part, int n)
{
  __shared__ int red[256];
  int base = blockIdx.x*1024;
  int s = 0;
  for (int k = threadIdx.x; k < 1024; k += 256) { int i = base+k; s += (i<n)? deg[i] : 0; }
  red[threadIdx.x] = s; __syncthreads();
  for (int off = 128; off > 0; off >>= 1) {
    if (threadIdx.x < off) red[threadIdx.x] += red[threadIdx.x+off];
    __syncthreads();
  }
  if (threadIdx.x == 0) part[blockIdx.x] = red[0];
}

__global__ void scan_p2(int* part, int* rowptr, int nb, int n)
{
  if (threadIdx.x == 0 && blockIdx.x == 0) {
    int run = 0;
    for (int b = 0; b < nb; ++b) { int v = part[b]; part[b] = run; run += v; }
    rowptr[n] = run;
  }
}

__global__ __launch_bounds__(256) void scan_p3(const int* __restrict__ deg, const int* __restrict__ part,
    int* __restrict__ rowptr, int* __restrict__ cursor, int n)
{
  __shared__ int ts[256];
  int tid = threadIdx.x;
  int base = blockIdx.x*1024 + tid*4;
  int v0=0,v1=0,v2=0,v3=0;
  if (base+0 < n) v0 = deg[base+0];
  if (base+1 < n) v1 = deg[base+1];
  if (base+2 < n) v2 = deg[base+2];
  if (base+3 < n) v3 = deg[base+3];
  ts[tid] = v0+v1+v2+v3; __syncthreads();
  for (int off = 1; off < 256; off <<= 1) {
    int t = (tid >= off) ? ts[tid-off] : 0;
    __syncthreads();
    ts[tid] += t;
    __syncthreads();
  }
  int ex = part[blockIdx.x] + (tid ? ts[tid-1] : 0);
  if (base+0 < n) { rowptr[base+0] = ex; cursor[base+0] = ex; ex += v0; }
  if (base+1 < n) { rowptr[base+1] = ex; cursor[base+1] = ex; ex += v1; }
  if (base+2 < n) { rowptr[base+2] = ex; cursor[base+2] = ex; ex += v2; }
  if (base+3 < n) { rowptr[base+3] = ex; cursor[base+3] = ex; ex += v3; }
}

__global__ __launch_bounds__(256) void scatter_kernel(const int* __restrict__ src, const int* __restrict__ dst,
    int* __restrict__ cursor, int* __restrict__ csr, int E)
{
  int e = blockIdx.x*blockDim.x + threadIdx.x;
  if (e >= E) return;
  int pos = atomicAdd(cursor + dst[e], 1);
  csr[pos] = src[e];
}

// ---------------- attention-logit precompute (reads bf16 xW) ----------------
__global__ __launch_bounds__(256) void al_init1(const ushort* __restrict__ xWb, const float* __restrict__ a_src,
    const float* __restrict__ a_dst, float* __restrict__ alS, float* __restrict__ alD, int n)
{
  int t = blockIdx.x*blockDim.x + threadIdx.x;
  if (t >= n*8) return;
  int h = t & 7;
  bf16x8 v = *(const bf16x8*)(xWb + (size_t)(t>>3)*64 + h*8);
  const float4* as4 = (const float4*)(a_src + h*8);
  const float4* ad4 = (const float4*)(a_dst + h*8);
  float4 s0 = as4[0], s1 = as4[1], d0 = ad4[0], d1 = ad4[1];
  float x0 = b2f((ushort)v[0]), x1 = b2f((ushort)v[1]), x2 = b2f((ushort)v[2]), x3 = b2f((ushort)v[3]);
  float x4 = b2f((ushort)v[4]), x5 = b2f((ushort)v[5]), x6 = b2f((ushort)v[6]), x7 = b2f((ushort)v[7]);
  alS[t] = x0*s0.x + x1*s0.y + x2*s0.z + x3*s0.w + x4*s1.x + x5*s1.y + x6*s1.z + x7*s1.w;
  alD[t] = x0*d0.x + x1*d0.y + x2*d0.z + x3*d0.w + x4*d1.x + x5*d1.y + x6*d1.z + x7*d1.w;
}

__global__ __launch_bounds__(256) void al_init2(const ushort* __restrict__ xWb, const float* __restrict__ a_src,
    const float* __restrict__ a_dst, float* __restrict__ alS, float* __restrict__ alD, int n)
{
  int node = blockIdx.x*blockDim.x + threadIdx.x;
  if (node >= n) return;
  const bf16x8* xw8 = (const bf16x8*)(xWb + (size_t)node*64);
  float s = 0.f, d = 0.f;
  #pragma unroll
  for (int q = 0; q < 8; ++q) {
    bf16x8 v = xw8[q];
    const float4* a4 = (const float4*)(a_src + q*8);
    const float4* b4 = (const float4*)(a_dst + q*8);
    float4 a0 = a4[0], a1 = a4[1], c0 = b4[0], c1 = b4[1];
    s += b2f((ushort)v[0])*a0.x + b2f((ushort)v[1])*a0.y + b2f((ushort)v[2])*a0.z + b2f((ushort)v[3])*a0.w
       + b2f((ushort)v[4])*a1.x + b2f((ushort)v[5])*a1.y + b2f((ushort)v[6])*a1.z + b2f((ushort)v[7])*a1.w;
    d += b2f((ushort)v[0])*c0.x + b2f((ushort)v[1])*c0.y + b2f((ushort)v[2])*c0.z + b2f((ushort)v[3])*c0.w
       + b2f((ushort)v[4])*c1.x + b2f((ushort)v[5])*c1.y + b2f((ushort)v[6])*c1.z + b2f((ushort)v[7])*c1.w;
  }
  alS[node] = s; alD[node] = d;
}

// ---------------- per-node gather + online softmax aggregation (bf16 xW, 2-edge unroll) ----------------
__global__ __launch_bounds__(256) void agg1(const ushort* __restrict__ xWb, const float* __restrict__ alS,
    const float* __restrict__ alD, const int* __restrict__ rowptr, const int* __restrict__ csr,
    const float* __restrict__ b, float* __restrict__ outp, int n)
{
  int node = blockIdx.x*4 + (threadIdx.x>>6);
  if (node >= n) return;
  int l = threadIdx.x & 63, h = l >> 3;
  float aD  = alD[(size_t)node*8 + h];
  float m   = lrelu(alS[(size_t)node*8 + h] + aD);
  float den = 1.f;
  float acc = b2f(xWb[(size_t)node*64 + l]);
  int p = rowptr[node], p1 = rowptr[node+1];
  for (; p+1 < p1; p += 2) {
    int s0 = csr[p], s1 = csr[p+1];
    float e0 = lrelu(alS[(size_t)s0*8 + h] + aD);
    float e1 = lrelu(alS[(size_t)s1*8 + h] + aD);
    float x0 = b2f(xWb[(size_t)s0*64 + l]);
    float x1 = b2f(xWb[(size_t)s1*64 + l]);
    float mn = fmaxf(m, fmaxf(e0, e1));
    float sc = __expf(m - mn);
    float w0 = __expf(e0 - mn);
    float w1 = __expf(e1 - mn);
    den = den*sc + w0 + w1;
    acc = acc*sc + w0*x0 + w1*x1;
    m = mn;
  }
  if (p < p1) {
    int s0 = csr[p];
    float e0 = lrelu(alS[(size_t)s0*8 + h] + aD);
    float x0 = b2f(xWb[(size_t)s0*64 + l]);
    float mn = fmaxf(m, e0);
    float sc = __expf(m - mn);
    float w0 = __expf(e0 - mn);
    den = den*sc + w0;
    acc = acc*sc + w0*x0;
    m = mn;
  }
  outp[(size_t)node*64 + l] = eluf(acc/(den + 1e-16f) + b[l]);
}

__global__ __launch_bounds__(256) void agg2(const ushort* __restrict__ xWb, const float* __restrict__ alS,
    const float* __restrict__ alD, const int* __restrict__ rowptr, const int* __restrict__ csr,
    const float* __restrict__ b, float* __restrict__ outp, int n)
{
  int node = blockIdx.x*4 + (threadIdx.x>>6);
  if (node >= n) return;
  int l = threadIdx.x & 63;
  float aD  = alD[node];
  float m   = lrelu(alS[node] + aD);
  float den = 1.f;
  float acc = b2f(xWb[(size_t)node*64 + l]);
  int p = rowptr[node], p1 = rowptr[node+1];
  for (; p+1 < p1; p += 2) {
    int s0 = csr[p], s1 = csr[p+1];
    float e0 = lrelu(alS[s0] + aD);
    float e1 = lrelu(alS[s1] + aD);
    float x0 = b2f(xWb[(size_t)s0*64 + l]);
    float x1 = b2f(xWb[(size_t)s1*64 + l]);
    float mn = fmaxf(m, fmaxf(e0, e1));
    float sc = __expf(m - mn);
    float w0 = __expf(e0 - mn);
    float w1 = __expf(e1 - mn);
    den = den*sc + w0 + w1;
    acc = acc*sc + w0*x0 + w1*x1;
    m = mn;
  }
  if (p < p1) {
    int s0 = csr[p];
    float e0 = lrelu(alS[s0] + aD);
    float x0 = b2f(xWb[(size_t)s0*64 + l]);
    float mn = fmaxf(m, e0);
    float sc = __expf(m - mn);
    float w0 = __expf(e0 - mn);
    den = den*sc + w0;
    acc = acc*sc + w0*x0;
    m = mn;
  }
  outp[(size_t)node*64 + l] = eluf(acc/(den + 1e-16f) + b[l]);
}

// W1[144][128] fp32 -> B-fragment-ordered bf16 image: [8 ntile][5 kstep][64 lane][8 bf16]
__global__ void w1_swizzle(const float* __restrict__ W1, ushort* __restrict__ w1sw)
{
  int t = blockIdx.x*blockDim.x + threadIdx.x;
  if (t >= 2560) return;
  int l = t & 63, nk = t >> 6;
  int nt = nk/5, ks = nk - nt*5;
  int ncol = nt*16 + (l&15);
  int kb = ks*32 + (l>>4)*8;
  union { ushort u[8]; uint4 q; } v;
  #pragma unroll
  for (int j = 0; j < 8; ++j) {
    int k = kb + j;
    float f = (k < 144) ? W1[k*128 + ncol] : 0.f;
    v.u[j] = f2bf(f);
  }
  ((uint4*)w1sw)[t] = v.q;
}

// ---------------- edge MLP via MFMA: wave per 16-edge tile ----------------
__global__ __launch_bounds__(256, 4) void edge_mlp_mfma(
    const ushort* __restrict__ h3b, const float* __restrict__ attr,
    const int* __restrict__ src, const int* __restrict__ dst,
    const ushort* __restrict__ w1sw, const float* __restrict__ b1,
    const float* __restrict__ W2, const float* __restrict__ b2,
    float* __restrict__ out, int E)
{
  __shared__ uint4 W1s[2560];            // 40 KB
  for (int i = threadIdx.x; i < 2560; i += 256) W1s[i] = ((const uint4*)w1sw)[i];
  __syncthreads();
  const bf16x8* Bf = (const bf16x8*)W1s;

  const int lane = threadIdx.x & 63;
  const int quad = lane >> 4, l15 = lane & 15;

  float w2a[8], w2b[8], bia[8];
  #pragma unroll
  for (int nt = 0; nt < 8; ++nt) {
    w2a[nt] = W2[(nt*16 + l15)*2 + 0];
    w2b[nt] = W2[(nt*16 + l15)*2 + 1];
    bia[nt] = b1[nt*16 + l15];
  }
  const float bb0 = b2[0], bb1 = b2[1];

  const int wid = (blockIdx.x*256 + threadIdx.x) >> 6;
  const int nw  = gridDim.x*4;
  const int nT  = (E + 15) >> 4;

  for (int t = wid; t < nT; t += nw) {
    const int tb = t*16;
    int e = tb + l15; if (e >= E) e = E - 1;
    const int s = src[e], d = dst[e];

    bf16x8 a0 = *(const bf16x8*)(h3b + (size_t)s*64 + quad*8);
    bf16x8 a1 = *(const bf16x8*)(h3b + (size_t)s*64 + 32 + quad*8);
    bf16x8 a2 = *(const bf16x8*)(h3b + (size_t)d*64 + quad*8);
    bf16x8 a3 = *(const bf16x8*)(h3b + (size_t)d*64 + 32 + quad*8);
    bf16x8 a4 = {};
    if (quad < 2) {
      const float4* ap = (const float4*)(attr + (size_t)e*16 + quad*8);
      float4 f0 = ap[0], f1 = ap[1];
      a4[0] = (short)f2bf(f0.x); a4[1] = (short)f2bf(f0.y);
      a4[2] = (short)f2bf(f0.z); a4[3] = (short)f2bf(f0.w);
      a4[4] = (short)f2bf(f1.x); a4[5] = (short)f2bf(f1.y);
      a4[6] = (short)f2bf(f1.z); a4[7] = (short)f2bf(f1.w);
    }

    f32x4 acc[8];
    #pragma unroll
    for (int nt = 0; nt < 8; ++nt) acc[nt] = (f32x4){0.f,0.f,0.f,0.f};

    #pragma unroll
    for (int nt = 0; nt < 8; ++nt) {
      acc[nt] = __builtin_amdgcn_mfma_f32_16x16x32_bf16(a0, Bf[(nt*5+0)*64 + lane], acc[nt], 0,0,0);
      acc[nt] = __builtin_amdgcn_mfma_f32_16x16x32_bf16(a1, Bf[(nt*5+1)*64 + lane], acc[nt], 0,0,0);
      acc[nt] = __builtin_amdgcn_mfma_f32_16x16x32_bf16(a2, Bf[(nt*5+2)*64 + lane], acc[nt], 0,0,0);
      acc[nt] = __builtin_amdgcn_mfma_f32_16x16x32_bf16(a3, Bf[(nt*5+3)*64 + lane], acc[nt], 0,0,0);
      acc[nt] = __builtin_amdgcn_mfma_f32_16x16x32_bf16(a4, Bf[(nt*5+4)*64 + lane], acc[nt], 0,0,0);
    }

    #pragma unroll
    for (int r = 0; r < 4; ++r) {
      float p0 = 0.f, p1 = 0.f;
      #pragma unroll
      for (int nt = 0; nt < 8; ++nt) {
        float hv = fmaxf(acc[nt][r] + bia[nt], 0.f);
        p0 = fmaf(hv, w2a[nt], p0);
        p1 = fmaf(hv, w2b[nt], p1);
      }
      #pragma unroll
      for (int off = 1; off < 16; off <<= 1) {
        p0 += __shfl_xor(p0, off, 64);
        p1 += __shfl_xor(p1, off, 64);
      }
      if (l15 == 0) {
        int eo = tb + quad*4 + r;
        if (eo < E) {
          p0 += bb0; p1 += bb1;
          float mm = fmaxf(p0, p1);
          float ls = mm + __logf(__expf(p0-mm) + __expf(p1-mm));
          ((float2*)out)[eo] = make_float2(p0 - ls, p1 - ls);
        }
      }
    }
  }
}

extern "C" void kernel_launch(void* const* d_in, const int* in_sizes, int n_in,
                              void* d_out, int out_size, void* d_ws, size_t ws_size,
                              hipStream_t stream) {
  const float* x      = (const float*)d_in[0];
  const int*   ei     = (const int*)d_in[1];
  const float* attr   = (const float*)d_in[2];
  const float* W1     = (const float*)d_in[3];
  const float* a_src1 = (const float*)d_in[4];
  const float* a_dst1 = (const float*)d_in[5];
  const float* b1     = (const float*)d_in[6];
  const float* W2     = (const float*)d_in[7];
  const float* a_src2 = (const float*)d_in[8];
  const float* a_dst2 = (const float*)d_in[9];
  const float* b2     = (const float*)d_in[10];
  const float* linW   = (const float*)d_in[11];
  const float* linb   = (const float*)d_in[12];
  const float* mW1    = (const float*)d_in[13];
  const float* mb1    = (const float*)d_in[14];
  const float* mW2    = (const float*)d_in[15];
  const float* mb2    = (const float*)d_in[16];
  float* out = (float*)d_out;

  int N = in_sizes[0] / 128;
  int E = in_sizes[1] / 2;
  const int* src = ei;
  const int* dst = ei + E;

  char* ws = (char*)d_ws;
  float*    bufH   = (float*)(ws);                 // 25.6 MB fp32: h1 / h2
  ushort*   bufAb  = (ushort*)(ws + 25600000);     // 12.8 MB bf16: xW1 / xW2
  ushort*   h3b    = (ushort*)(ws + 38400000);     // 12.8 MB bf16: h3
  int*      csr    = (int*)  (ws + 51200000);      // 6.4 MB
  float*    alS    = (float*)(ws + 57600000);      // 3.2 MB (layer1: N*8, layer2: N)
  float*    alD    = (float*)(ws + 60800000);      // 3.2 MB
  int*      rowptr = (int*)  (ws + 64000000);
  int*      degcur = (int*)  (ws + 64400064);
  int*      part   = (int*)  (ws + 64800064);
  ushort*   w1sw   = (ushort*)(ws + 64900096);     // 40 KB

  int gN4 = (N + 3) / 4;
  int gNH = (N*8 + 255) / 256;
  int gN  = (N + 255) / 256;
  int gE  = (E + 255) / 256;
  int nChunk = (N + 1023) / 1024;

  // ---- CSR build ----
  hipMemsetAsync(degcur, 0, (size_t)N*sizeof(int), stream);
  hist_kernel<<<gE, 256, 0, stream>>>(dst, degcur, E);
  scan_p1<<<nChunk, 256, 0, stream>>>(degcur, part, N);
  scan_p2<<<1, 64, 0, stream>>>(part, rowptr, nChunk, N);
  scan_p3<<<nChunk, 256, 0, stream>>>(degcur, part, rowptr, degcur, N);
  scatter_kernel<<<gE, 256, 0, stream>>>(src, dst, degcur, csr, E);
  w1_swizzle<<<10, 256, 0, stream>>>(mW1, w1sw);

  // ---- layer 1 ----
  gemm_n64<<<gN4, 256, 0, stream>>>(x, W1, nullptr, bufAb, N, 128);
  al_init1<<<gNH, 256, 0, stream>>>(bufAb, a_src1, a_dst1, alS, alD, N);
  agg1<<<gN4, 256, 0, stream>>>(bufAb, alS, alD, rowptr, csr, b1, bufH, N);
  // ---- layer 2 ----
  gemm_n64<<<gN4, 256, 0, stream>>>(bufH, W2, nullptr, bufAb, N, 64);
  al_init2<<<gN, 256, 0, stream>>>(bufAb, a_src2, a_dst2, alS, alD, N);
  agg2<<<gN4, 256, 0, stream>>>(bufAb, alS, alD, rowptr, csr, b2, bufH, N);
  // ---- linear -> h3 bf16 ----
  gemm_n64<<<gN4, 256, 0, stream>>>(bufH, linW, linb, h3b, N, 64);
  // ---- fused edge MLP (attr converted in-kernel) ----
  edge_mlp_mfma<<<2048, 256, 0, stream>>>(h3b, attr, src, dst, w1sw, mb1, mW2, mb2, out, E);
}

// Round 5
// 1213.580 us; speedup vs baseline: 1.2439x; 1.2439x over previous
//
#include <hip/hip_runtime.h>
#include <math.h>

#define DEV_INLINE __device__ __forceinline__
typedef unsigned short ushort;
typedef __attribute__((ext_vector_type(8))) short bf16x8;
typedef __attribute__((ext_vector_type(4))) float f32x4;

DEV_INLINE float lrelu(float x){ return x > 0.f ? x : 0.2f*x; }
DEV_INLINE float eluf(float x){ return x>0.f? x : (__expf(x)-1.f); }
DEV_INLINE ushort f2bf(float f){
  unsigned u = __float_as_uint(f);
  return (ushort)((u + 0x7FFFu + ((u>>16)&1u)) >> 16);   // RNE
}
DEV_INLINE float b2f(ushort u){ return __uint_as_float(((unsigned)u)<<16); }

// ---------------- node GEMM: Cb[n][64] = bf16(A[n][K] @ W[K][64] (+bias)) ----------------
// mode 1: also emit 8-head logits (alS/alD [n][8]); mode 2: 1-head logits [n]
__global__ __launch_bounds__(256) void gemm_n64(const float* __restrict__ A, const float* __restrict__ W,
    const float* __restrict__ bias, ushort* __restrict__ Cb, int n, int K,
    int mode, const float* __restrict__ asrc, const float* __restrict__ adst,
    float* __restrict__ alS, float* __restrict__ alD)
{
  int j = threadIdx.x & 63;
  int node = blockIdx.x*4 + (threadIdx.x>>6);
  if (node >= n) return;   // wave-uniform (one node per wave)
  const float4* A4 = (const float4*)(A + (size_t)node*K);
  float acc = 0.f;
  int K4 = K>>2;
  for (int k4 = 0; k4 < K4; ++k4) {
    float4 a = A4[k4];
    const float* w = W + k4*256 + j;
    acc = fmaf(a.x, w[0],   acc);
    acc = fmaf(a.y, w[64],  acc);
    acc = fmaf(a.z, w[128], acc);
    acc = fmaf(a.w, w[192], acc);
  }
  if (bias) acc += bias[j];
  Cb[(size_t)node*64 + j] = f2bf(acc);
  if (mode == 1) {
    float s = acc * asrc[j];
    float d = acc * adst[j];
    #pragma unroll
    for (int off = 1; off < 8; off <<= 1) { s += __shfl_xor(s, off, 64); d += __shfl_xor(d, off, 64); }
    if ((j & 7) == 0) {
      alS[(size_t)node*8 + (j>>3)] = s;
      alD[(size_t)node*8 + (j>>3)] = d;
    }
  } else if (mode == 2) {
    float s = acc * asrc[j];
    float d = acc * adst[j];
    #pragma unroll
    for (int off = 1; off < 64; off <<= 1) { s += __shfl_xor(s, off, 64); d += __shfl_xor(d, off, 64); }
    if (j == 0) { alS[node] = s; alD[node] = d; }
  }
}

// ---------------- CSR build (grouped by dst) ----------------
__global__ __launch_bounds__(256) void hist_kernel(const int* __restrict__ dst, int* __restrict__ deg, int E)
{
  int e = blockIdx.x*blockDim.x + threadIdx.x;
  if (e < E) atomicAdd(deg + dst[e], 1);
}

__global__ __launch_bounds__(256) void scan_p1(const int* __restrict__ deg, int* __restrict__ part, int n)
{
  __shared__ int red[256];
  int base = blockIdx.x*1024;
  int s = 0;
  for (int k = threadIdx.x; k < 1024; k += 256) { int i = base+k; s += (i<n)? deg[i] : 0; }
  red[threadIdx.x] = s; __syncthreads();
  for (int off = 128; off > 0; off >>= 1) {
    if (threadIdx.x < off) red[threadIdx.x] += red[threadIdx.x+off];
    __syncthreads();
  }
  if (threadIdx.x == 0) part[blockIdx.x] = red[0];
}

__global__ void scan_p2(int* part, int* rowptr, int nb, int n)
{
  if (threadIdx.x == 0 && blockIdx.x == 0) {
    int run = 0;
    for (int b = 0; b < nb; ++b) { int v = part[b]; part[b] = run; run += v; }
    rowptr[n] = run;
  }
}

__global__ __launch_bounds__(256) void scan_p3(const int* __restrict__ deg, const int* __restrict__ part,
    int* __restrict__ rowptr, int* __restrict__ cursor, int n)
{
  __shared__ int ts[256];
  int tid = threadIdx.x;
  int base = blockIdx.x*1024 + tid*4;
  int v0=0,v1=0,v2=0,v3=0;
  if (base+0 < n) v0 = deg[base+0];
  if (base+1 < n) v1 = deg[base+1];
  if (base+2 < n) v2 = deg[base+2];
  if (base+3 < n) v3 = deg[base+3];
  ts[tid] = v0+v1+v2+v3; __syncthreads();
  for (int off = 1; off < 256; off <<= 1) {
    int t = (tid >= off) ? ts[tid-off] : 0;
    __syncthreads();
    ts[tid] += t;
    __syncthreads();
  }
  int ex = part[blockIdx.x] + (tid ? ts[tid-1] : 0);
  if (base+0 < n) { rowptr[base+0] = ex; cursor[base+0] = ex; ex += v0; }
  if (base+1 < n) { rowptr[base+1] = ex; cursor[base+1] = ex; ex += v1; }
  if (base+2 < n) { rowptr[base+2] = ex; cursor[base+2] = ex; ex += v2; }
  if (base+3 < n) { rowptr[base+3] = ex; cursor[base+3] = ex; ex += v3; }
}

__global__ __launch_bounds__(256) void scatter_kernel(const int* __restrict__ src, const int* __restrict__ dst,
    int* __restrict__ cursor, int* __restrict__ csr, int E)
{
  int e = blockIdx.x*blockDim.x + threadIdx.x;
  if (e >= E) return;
  int pos = atomicAdd(cursor + dst[e], 1);
  csr[pos] = src[e];
}

// ---------------- per-node gather + online softmax aggregation (bf16 xW, 2-edge unroll) ----------------
__global__ __launch_bounds__(256) void agg1(const ushort* __restrict__ xWb, const float* __restrict__ alS,
    const float* __restrict__ alD, const int* __restrict__ rowptr, const int* __restrict__ csr,
    const float* __restrict__ b, float* __restrict__ outp, int n)
{
  int node = blockIdx.x*4 + (threadIdx.x>>6);
  if (node >= n) return;
  int l = threadIdx.x & 63, h = l >> 3;
  float aD  = alD[(size_t)node*8 + h];
  float m   = lrelu(alS[(size_t)node*8 + h] + aD);
  float den = 1.f;
  float acc = b2f(xWb[(size_t)node*64 + l]);
  int p = rowptr[node], p1 = rowptr[node+1];
  for (; p+1 < p1; p += 2) {
    int s0 = csr[p], s1 = csr[p+1];
    float e0 = lrelu(alS[(size_t)s0*8 + h] + aD);
    float e1 = lrelu(alS[(size_t)s1*8 + h] + aD);
    float x0 = b2f(xWb[(size_t)s0*64 + l]);
    float x1 = b2f(xWb[(size_t)s1*64 + l]);
    float mn = fmaxf(m, fmaxf(e0, e1));
    float sc = __expf(m - mn);
    float w0 = __expf(e0 - mn);
    float w1 = __expf(e1 - mn);
    den = den*sc + w0 + w1;
    acc = acc*sc + w0*x0 + w1*x1;
    m = mn;
  }
  if (p < p1) {
    int s0 = csr[p];
    float e0 = lrelu(alS[(size_t)s0*8 + h] + aD);
    float x0 = b2f(xWb[(size_t)s0*64 + l]);
    float mn = fmaxf(m, e0);
    float sc = __expf(m - mn);
    float w0 = __expf(e0 - mn);
    den = den*sc + w0;
    acc = acc*sc + w0*x0;
    m = mn;
  }
  outp[(size_t)node*64 + l] = eluf(acc/(den + 1e-16f) + b[l]);
}

__global__ __launch_bounds__(256) void agg2(const ushort* __restrict__ xWb, const float* __restrict__ alS,
    const float* __restrict__ alD, const int* __restrict__ rowptr, const int* __restrict__ csr,
    const float* __restrict__ b, float* __restrict__ outp, int n)
{
  int node = blockIdx.x*4 + (threadIdx.x>>6);
  if (node >= n) return;
  int l = threadIdx.x & 63;
  float aD  = alD[node];
  float m   = lrelu(alS[node] + aD);
  float den = 1.f;
  float acc = b2f(xWb[(size_t)node*64 + l]);
  int p = rowptr[node], p1 = rowptr[node+1];
  for (; p+1 < p1; p += 2) {
    int s0 = csr[p], s1 = csr[p+1];
    float e0 = lrelu(alS[s0] + aD);
    float e1 = lrelu(alS[s1] + aD);
    float x0 = b2f(xWb[(size_t)s0*64 + l]);
    float x1 = b2f(xWb[(size_t)s1*64 + l]);
    float mn = fmaxf(m, fmaxf(e0, e1));
    float sc = __expf(m - mn);
    float w0 = __expf(e0 - mn);
    float w1 = __expf(e1 - mn);
    den = den*sc + w0 + w1;
    acc = acc*sc + w0*x0 + w1*x1;
    m = mn;
  }
  if (p < p1) {
    int s0 = csr[p];
    float e0 = lrelu(alS[s0] + aD);
    float x0 = b2f(xWb[(size_t)s0*64 + l]);
    float mn = fmaxf(m, e0);
    float sc = __expf(m - mn);
    float w0 = __expf(e0 - mn);
    den = den*sc + w0;
    acc = acc*sc + w0*x0;
    m = mn;
  }
  outp[(size_t)node*64 + l] = eluf(acc/(den + 1e-16f) + b[l]);
}

// W1[144][128] fp32 -> B-fragment-ordered bf16 image: [8 ntile][5 kstep][64 lane][8 bf16]
__global__ void w1_swizzle(const float* __restrict__ W1, ushort* __restrict__ w1sw)
{
  int t = blockIdx.x*blockDim.x + threadIdx.x;
  if (t >= 2560) return;
  int l = t & 63, nk = t >> 6;
  int nt = nk/5, ks = nk - nt*5;
  int ncol = nt*16 + (l&15);
  int kb = ks*32 + (l>>4)*8;
  union { ushort u[8]; uint4 q; } v;
  #pragma unroll
  for (int j = 0; j < 8; ++j) {
    int k = kb + j;
    float f = (k < 144) ? W1[k*128 + ncol] : 0.f;
    v.u[j] = f2bf(f);
  }
  ((uint4*)w1sw)[t] = v.q;
}

// ---------------- edge MLP via MFMA: wave per 16-edge tile ----------------
// NOTE: deliberately low occupancy (no min-waves bound, grid 1024): at ~11% occupancy
// the random h3b gathers stay L2-resident (R3: FETCH 180 MB, 233 us); at 45% occupancy
// L2 thrashes (R4: FETCH 1.77 GB, 578 us).
__global__ __launch_bounds__(256) void edge_mlp_mfma(
    const ushort* __restrict__ h3b, const float* __restrict__ attr,
    const int* __restrict__ src, const int* __restrict__ dst,
    const ushort* __restrict__ w1sw, const float* __restrict__ b1,
    const float* __restrict__ W2, const float* __restrict__ b2,
    float* __restrict__ out, int E)
{
  __shared__ uint4 W1s[2560];            // 40 KB
  for (int i = threadIdx.x; i < 2560; i += 256) W1s[i] = ((const uint4*)w1sw)[i];
  __syncthreads();
  const bf16x8* Bf = (const bf16x8*)W1s;

  const int lane = threadIdx.x & 63;
  const int quad = lane >> 4, l15 = lane & 15;

  float w2a[8], w2b[8], bia[8];
  #pragma unroll
  for (int nt = 0; nt < 8; ++nt) {
    w2a[nt] = W2[(nt*16 + l15)*2 + 0];
    w2b[nt] = W2[(nt*16 + l15)*2 + 1];
    bia[nt] = b1[nt*16 + l15];
  }
  const float bb0 = b2[0], bb1 = b2[1];

  const int wid = (blockIdx.x*256 + threadIdx.x) >> 6;
  const int nw  = gridDim.x*4;
  const int nT  = (E + 15) >> 4;

  for (int t = wid; t < nT; t += nw) {
    const int tb = t*16;
    int e = tb + l15; if (e >= E) e = E - 1;
    const int s = src[e], d = dst[e];

    bf16x8 a0 = *(const bf16x8*)(h3b + (size_t)s*64 + quad*8);
    bf16x8 a1 = *(const bf16x8*)(h3b + (size_t)s*64 + 32 + quad*8);
    bf16x8 a2 = *(const bf16x8*)(h3b + (size_t)d*64 + quad*8);
    bf16x8 a3 = *(const bf16x8*)(h3b + (size_t)d*64 + 32 + quad*8);
    bf16x8 a4 = {};
    if (quad < 2) {
      const float4* ap = (const float4*)(attr + (size_t)e*16 + quad*8);
      float4 f0 = ap[0], f1 = ap[1];
      a4[0] = (short)f2bf(f0.x); a4[1] = (short)f2bf(f0.y);
      a4[2] = (short)f2bf(f0.z); a4[3] = (short)f2bf(f0.w);
      a4[4] = (short)f2bf(f1.x); a4[5] = (short)f2bf(f1.y);
      a4[6] = (short)f2bf(f1.z); a4[7] = (short)f2bf(f1.w);
    }

    f32x4 acc[8];
    #pragma unroll
    for (int nt = 0; nt < 8; ++nt) acc[nt] = (f32x4){0.f,0.f,0.f,0.f};

    #pragma unroll
    for (int nt = 0; nt < 8; ++nt) {
      acc[nt] = __builtin_amdgcn_mfma_f32_16x16x32_bf16(a0, Bf[(nt*5+0)*64 + lane], acc[nt], 0,0,0);
      acc[nt] = __builtin_amdgcn_mfma_f32_16x16x32_bf16(a1, Bf[(nt*5+1)*64 + lane], acc[nt], 0,0,0);
      acc[nt] = __builtin_amdgcn_mfma_f32_16x16x32_bf16(a2, Bf[(nt*5+2)*64 + lane], acc[nt], 0,0,0);
      acc[nt] = __builtin_amdgcn_mfma_f32_16x16x32_bf16(a3, Bf[(nt*5+3)*64 + lane], acc[nt], 0,0,0);
      acc[nt] = __builtin_amdgcn_mfma_f32_16x16x32_bf16(a4, Bf[(nt*5+4)*64 + lane], acc[nt], 0,0,0);
    }

    #pragma unroll
    for (int r = 0; r < 4; ++r) {
      float p0 = 0.f, p1 = 0.f;
      #pragma unroll
      for (int nt = 0; nt < 8; ++nt) {
        float hv = fmaxf(acc[nt][r] + bia[nt], 0.f);
        p0 = fmaf(hv, w2a[nt], p0);
        p1 = fmaf(hv, w2b[nt], p1);
      }
      #pragma unroll
      for (int off = 1; off < 16; off <<= 1) {
        p0 += __shfl_xor(p0, off, 64);
        p1 += __shfl_xor(p1, off, 64);
      }
      if (l15 == 0) {
        int eo = tb + quad*4 + r;
        if (eo < E) {
          p0 += bb0; p1 += bb1;
          float mm = fmaxf(p0, p1);
          float ls = mm + __logf(__expf(p0-mm) + __expf(p1-mm));
          ((float2*)out)[eo] = make_float2(p0 - ls, p1 - ls);
        }
      }
    }
  }
}

extern "C" void kernel_launch(void* const* d_in, const int* in_sizes, int n_in,
                              void* d_out, int out_size, void* d_ws, size_t ws_size,
                              hipStream_t stream) {
  const float* x      = (const float*)d_in[0];
  const int*   ei     = (const int*)d_in[1];
  const float* attr   = (const float*)d_in[2];
  const float* W1     = (const float*)d_in[3];
  const float* a_src1 = (const float*)d_in[4];
  const float* a_dst1 = (const float*)d_in[5];
  const float* b1     = (const float*)d_in[6];
  const float* W2     = (const float*)d_in[7];
  const float* a_src2 = (const float*)d_in[8];
  const float* a_dst2 = (const float*)d_in[9];
  const float* b2     = (const float*)d_in[10];
  const float* linW   = (const float*)d_in[11];
  const float* linb   = (const float*)d_in[12];
  const float* mW1    = (const float*)d_in[13];
  const float* mb1    = (const float*)d_in[14];
  const float* mW2    = (const float*)d_in[15];
  const float* mb2    = (const float*)d_in[16];
  float* out = (float*)d_out;

  int N = in_sizes[0] / 128;
  int E = in_sizes[1] / 2;
  const int* src = ei;
  const int* dst = ei + E;

  char* ws = (char*)d_ws;
  float*    bufH   = (float*)(ws);                 // 25.6 MB fp32: h1 / h2
  ushort*   bufAb  = (ushort*)(ws + 25600000);     // 12.8 MB bf16: xW1 / xW2
  ushort*   h3b    = (ushort*)(ws + 38400000);     // 12.8 MB bf16: h3
  int*      csr    = (int*)  (ws + 51200000);      // 6.4 MB
  float*    alS    = (float*)(ws + 57600000);      // 3.2 MB (layer1: N*8, layer2: N)
  float*    alD    = (float*)(ws + 60800000);      // 3.2 MB
  int*      rowptr = (int*)  (ws + 64000000);
  int*      degcur = (int*)  (ws + 64400064);
  int*      part   = (int*)  (ws + 64800064);
  ushort*   w1sw   = (ushort*)(ws + 64900096);     // 40 KB

  int gN4 = (N + 3) / 4;
  int gE  = (E + 255) / 256;
  int nChunk = (N + 1023) / 1024;

  // ---- CSR build ----
  hipMemsetAsync(degcur, 0, (size_t)N*sizeof(int), stream);
  hist_kernel<<<gE, 256, 0, stream>>>(dst, degcur, E);
  scan_p1<<<nChunk, 256, 0, stream>>>(degcur, part, N);
  scan_p2<<<1, 64, 0, stream>>>(part, rowptr, nChunk, N);
  scan_p3<<<nChunk, 256, 0, stream>>>(degcur, part, rowptr, degcur, N);
  scatter_kernel<<<gE, 256, 0, stream>>>(src, dst, degcur, csr, E);
  w1_swizzle<<<10, 256, 0, stream>>>(mW1, w1sw);

  // ---- layer 1 (gemm + fused logits) ----
  gemm_n64<<<gN4, 256, 0, stream>>>(x, W1, nullptr, bufAb, N, 128, 1, a_src1, a_dst1, alS, alD);
  agg1<<<gN4, 256, 0, stream>>>(bufAb, alS, alD, rowptr, csr, b1, bufH, N);
  // ---- layer 2 ----
  gemm_n64<<<gN4, 256, 0, stream>>>(bufH, W2, nullptr, bufAb, N, 64, 2, a_src2, a_dst2, alS, alD);
  agg2<<<gN4, 256, 0, stream>>>(bufAb, alS, alD, rowptr, csr, b2, bufH, N);
  // ---- linear -> h3 bf16 ----
  gemm_n64<<<gN4, 256, 0, stream>>>(bufH, linW, linb, h3b, N, 64, 0, nullptr, nullptr, nullptr, nullptr);
  // ---- fused edge MLP (attr converted in-kernel; low-occupancy by design) ----
  edge_mlp_mfma<<<1024, 256, 0, stream>>>(h3b, attr, src, dst, w1sw, mb1, mW2, mb2, out, E);
}

// Round 6
// 1153.089 us; speedup vs baseline: 1.3091x; 1.0525x over previous
//
#include <hip/hip_runtime.h>
#include <math.h>

#define DEV_INLINE __device__ __forceinline__
typedef unsigned short ushort;
typedef __attribute__((ext_vector_type(8))) short bf16x8;
typedef __attribute__((ext_vector_type(4))) float f32x4;

DEV_INLINE float lrelu(float x){ return x > 0.f ? x : 0.2f*x; }
DEV_INLINE float eluf(float x){ return x>0.f? x : (__expf(x)-1.f); }
DEV_INLINE ushort f2bf(float f){
  unsigned u = __float_as_uint(f);
  return (ushort)((u + 0x7FFFu + ((u>>16)&1u)) >> 16);   // RNE
}
DEV_INLINE float b2f(ushort u){ return __uint_as_float(((unsigned)u)<<16); }

// ---------------- node GEMM: Cb[n][64] = bf16(A[n][K] @ W[K][64] (+bias)) ----------------
// mode 1: also emit 8-head logits (alS/alD [n][8]); mode 2: 1-head logits [n]
__global__ __launch_bounds__(256) void gemm_n64(const float* __restrict__ A, const float* __restrict__ W,
    const float* __restrict__ bias, ushort* __restrict__ Cb, int n, int K,
    int mode, const float* __restrict__ asrc, const float* __restrict__ adst,
    float* __restrict__ alS, float* __restrict__ alD)
{
  int j = threadIdx.x & 63;
  int node = blockIdx.x*4 + (threadIdx.x>>6);
  if (node >= n) return;   // wave-uniform (one node per wave)
  const float4* A4 = (const float4*)(A + (size_t)node*K);
  float acc = 0.f;
  int K4 = K>>2;
  for (int k4 = 0; k4 < K4; ++k4) {
    float4 a = A4[k4];
    const float* w = W + k4*256 + j;
    acc = fmaf(a.x, w[0],   acc);
    acc = fmaf(a.y, w[64],  acc);
    acc = fmaf(a.z, w[128], acc);
    acc = fmaf(a.w, w[192], acc);
  }
  if (bias) acc += bias[j];
  Cb[(size_t)node*64 + j] = f2bf(acc);
  if (mode == 1) {
    float s = acc * asrc[j];
    float d = acc * adst[j];
    #pragma unroll
    for (int off = 1; off < 8; off <<= 1) { s += __shfl_xor(s, off, 64); d += __shfl_xor(d, off, 64); }
    if ((j & 7) == 0) {
      alS[(size_t)node*8 + (j>>3)] = s;
      alD[(size_t)node*8 + (j>>3)] = d;
    }
  } else if (mode == 2) {
    float s = acc * asrc[j];
    float d = acc * adst[j];
    #pragma unroll
    for (int off = 1; off < 64; off <<= 1) { s += __shfl_xor(s, off, 64); d += __shfl_xor(d, off, 64); }
    if (j == 0) { alS[node] = s; alD[node] = d; }
  }
}

// ---------------- CSR build (grouped by dst) ----------------
__global__ __launch_bounds__(256) void hist_kernel(const int* __restrict__ dst, int* __restrict__ deg, int E)
{
  int e = blockIdx.x*blockDim.x + threadIdx.x;
  if (e < E) atomicAdd(deg + dst[e], 1);
}

__global__ __launch_bounds__(256) void scan_p1(const int* __restrict__ deg, int* __restrict__ part, int n)
{
  __shared__ int red[256];
  int base = blockIdx.x*1024;
  int s = 0;
  for (int k = threadIdx.x; k < 1024; k += 256) { int i = base+k; s += (i<n)? deg[i] : 0; }
  red[threadIdx.x] = s; __syncthreads();
  for (int off = 128; off > 0; off >>= 1) {
    if (threadIdx.x < off) red[threadIdx.x] += red[threadIdx.x+off];
    __syncthreads();
  }
  if (threadIdx.x == 0) part[blockIdx.x] = red[0];
}

// parallel exclusive scan of nb (<=128) block partials
__global__ __launch_bounds__(128) void scan_p2(int* part, int* rowptr, int nb, int n)
{
  __shared__ int ts[128];
  int tid = threadIdx.x;
  int v = (tid < nb) ? part[tid] : 0;
  ts[tid] = v; __syncthreads();
  #pragma unroll
  for (int off = 1; off < 128; off <<= 1) {
    int t = (tid >= off) ? ts[tid-off] : 0;
    __syncthreads();
    ts[tid] += t;
    __syncthreads();
  }
  if (tid < nb) part[tid] = ts[tid] - v;   // exclusive
  if (tid == 127) rowptr[n] = ts[127];     // total
}

__global__ __launch_bounds__(256) void scan_p3(const int* __restrict__ deg, const int* __restrict__ part,
    int* __restrict__ rowptr, int* __restrict__ cursor, int n)
{
  __shared__ int ts[256];
  int tid = threadIdx.x;
  int base = blockIdx.x*1024 + tid*4;
  int v0=0,v1=0,v2=0,v3=0;
  if (base+0 < n) v0 = deg[base+0];
  if (base+1 < n) v1 = deg[base+1];
  if (base+2 < n) v2 = deg[base+2];
  if (base+3 < n) v3 = deg[base+3];
  ts[tid] = v0+v1+v2+v3; __syncthreads();
  for (int off = 1; off < 256; off <<= 1) {
    int t = (tid >= off) ? ts[tid-off] : 0;
    __syncthreads();
    ts[tid] += t;
    __syncthreads();
  }
  int ex = part[blockIdx.x] + (tid ? ts[tid-1] : 0);
  if (base+0 < n) { rowptr[base+0] = ex; cursor[base+0] = ex; ex += v0; }
  if (base+1 < n) { rowptr[base+1] = ex; cursor[base+1] = ex; ex += v1; }
  if (base+2 < n) { rowptr[base+2] = ex; cursor[base+2] = ex; ex += v2; }
  if (base+3 < n) { rowptr[base+3] = ex; cursor[base+3] = ex; ex += v3; }
}

__global__ __launch_bounds__(256) void scatter_kernel(const int* __restrict__ src, const int* __restrict__ dst,
    int* __restrict__ cursor, int* __restrict__ csr, int E)
{
  int e = blockIdx.x*blockDim.x + threadIdx.x;
  if (e >= E) return;
  int pos = atomicAdd(cursor + dst[e], 1);
  csr[pos] = src[e];
}

// ---------------- per-node gather + online softmax aggregation (bf16 xW, 4-edge unroll) ----------------
__global__ __launch_bounds__(256) void agg1(const ushort* __restrict__ xWb, const float* __restrict__ alS,
    const float* __restrict__ alD, const int* __restrict__ rowptr, const int* __restrict__ csr,
    const float* __restrict__ b, float* __restrict__ outp, int n)
{
  int node = blockIdx.x*4 + (threadIdx.x>>6);
  if (node >= n) return;
  int l = threadIdx.x & 63, h = l >> 3;
  float aD  = alD[(size_t)node*8 + h];
  float m   = lrelu(alS[(size_t)node*8 + h] + aD);
  float den = 1.f;
  float acc = b2f(xWb[(size_t)node*64 + l]);
  int p = rowptr[node], p1 = rowptr[node+1];
  for (; p+3 < p1; p += 4) {
    int s0 = csr[p], s1 = csr[p+1], s2 = csr[p+2], s3 = csr[p+3];
    float e0 = lrelu(alS[(size_t)s0*8 + h] + aD);
    float e1 = lrelu(alS[(size_t)s1*8 + h] + aD);
    float e2 = lrelu(alS[(size_t)s2*8 + h] + aD);
    float e3 = lrelu(alS[(size_t)s3*8 + h] + aD);
    float x0 = b2f(xWb[(size_t)s0*64 + l]);
    float x1 = b2f(xWb[(size_t)s1*64 + l]);
    float x2 = b2f(xWb[(size_t)s2*64 + l]);
    float x3 = b2f(xWb[(size_t)s3*64 + l]);
    float mn = fmaxf(fmaxf(m, fmaxf(e0, e1)), fmaxf(e2, e3));
    float sc = __expf(m - mn);
    float w0 = __expf(e0 - mn), w1 = __expf(e1 - mn);
    float w2 = __expf(e2 - mn), w3 = __expf(e3 - mn);
    den = den*sc + (w0 + w1) + (w2 + w3);
    acc = acc*sc + (w0*x0 + w1*x1) + (w2*x2 + w3*x3);
    m = mn;
  }
  for (; p < p1; ++p) {
    int s0 = csr[p];
    float e0 = lrelu(alS[(size_t)s0*8 + h] + aD);
    float x0 = b2f(xWb[(size_t)s0*64 + l]);
    float mn = fmaxf(m, e0);
    float sc = __expf(m - mn);
    float w0 = __expf(e0 - mn);
    den = den*sc + w0;
    acc = acc*sc + w0*x0;
    m = mn;
  }
  outp[(size_t)node*64 + l] = eluf(acc/(den + 1e-16f) + b[l]);
}

__global__ __launch_bounds__(256) void agg2(const ushort* __restrict__ xWb, const float* __restrict__ alS,
    const float* __restrict__ alD, const int* __restrict__ rowptr, const int* __restrict__ csr,
    const float* __restrict__ b, float* __restrict__ outp, int n)
{
  int node = blockIdx.x*4 + (threadIdx.x>>6);
  if (node >= n) return;
  int l = threadIdx.x & 63;
  float aD  = alD[node];
  float m   = lrelu(alS[node] + aD);
  float den = 1.f;
  float acc = b2f(xWb[(size_t)node*64 + l]);
  int p = rowptr[node], p1 = rowptr[node+1];
  for (; p+3 < p1; p += 4) {
    int s0 = csr[p], s1 = csr[p+1], s2 = csr[p+2], s3 = csr[p+3];
    float e0 = lrelu(alS[s0] + aD);
    float e1 = lrelu(alS[s1] + aD);
    float e2 = lrelu(alS[s2] + aD);
    float e3 = lrelu(alS[s3] + aD);
    float x0 = b2f(xWb[(size_t)s0*64 + l]);
    float x1 = b2f(xWb[(size_t)s1*64 + l]);
    float x2 = b2f(xWb[(size_t)s2*64 + l]);
    float x3 = b2f(xWb[(size_t)s3*64 + l]);
    float mn = fmaxf(fmaxf(m, fmaxf(e0, e1)), fmaxf(e2, e3));
    float sc = __expf(m - mn);
    float w0 = __expf(e0 - mn), w1 = __expf(e1 - mn);
    float w2 = __expf(e2 - mn), w3 = __expf(e3 - mn);
    den = den*sc + (w0 + w1) + (w2 + w3);
    acc = acc*sc + (w0*x0 + w1*x1) + (w2*x2 + w3*x3);
    m = mn;
  }
  for (; p < p1; ++p) {
    int s0 = csr[p];
    float e0 = lrelu(alS[s0] + aD);
    float x0 = b2f(xWb[(size_t)s0*64 + l]);
    float mn = fmaxf(m, e0);
    float sc = __expf(m - mn);
    float w0 = __expf(e0 - mn);
    den = den*sc + w0;
    acc = acc*sc + w0*x0;
    m = mn;
  }
  outp[(size_t)node*64 + l] = eluf(acc/(den + 1e-16f) + b[l]);
}

// W1[144][128] fp32 -> B-fragment-ordered bf16 image: [8 ntile][5 kstep][64 lane][8 bf16]
__global__ void w1_swizzle(const float* __restrict__ W1, ushort* __restrict__ w1sw)
{
  int t = blockIdx.x*blockDim.x + threadIdx.x;
  if (t >= 2560) return;
  int l = t & 63, nk = t >> 6;
  int nt = nk/5, ks = nk - nt*5;
  int ncol = nt*16 + (l&15);
  int kb = ks*32 + (l>>4)*8;
  union { ushort u[8]; uint4 q; } v;
  #pragma unroll
  for (int j = 0; j < 8; ++j) {
    int k = kb + j;
    float f = (k < 144) ? W1[k*128 + ncol] : 0.f;
    v.u[j] = f2bf(f);
  }
  ((uint4*)w1sw)[t] = v.q;
}

// ---------------- edge MLP via MFMA: wave per 16-edge tile ----------------
// Launch config note: natural VGPR (132) — do NOT add a min-waves bound; R4's
// __launch_bounds__(256,4) forced VGPR=64 and spilled the accumulators
// (WRITE_SIZE 12.5 MB -> 264 MB, 2.2x slower). Grid 2048 doubles waves/SIMD
// (1 -> 2) for latency hiding without spills.
__global__ __launch_bounds__(256) void edge_mlp_mfma(
    const ushort* __restrict__ h3b, const float* __restrict__ attr,
    const int* __restrict__ src, const int* __restrict__ dst,
    const ushort* __restrict__ w1sw, const float* __restrict__ b1,
    const float* __restrict__ W2, const float* __restrict__ b2,
    float* __restrict__ out, int E)
{
  __shared__ uint4 W1s[2560];            // 40 KB
  for (int i = threadIdx.x; i < 2560; i += 256) W1s[i] = ((const uint4*)w1sw)[i];
  __syncthreads();
  const bf16x8* Bf = (const bf16x8*)W1s;

  const int lane = threadIdx.x & 63;
  const int quad = lane >> 4, l15 = lane & 15;

  float w2a[8], w2b[8], bia[8];
  #pragma unroll
  for (int nt = 0; nt < 8; ++nt) {
    w2a[nt] = W2[(nt*16 + l15)*2 + 0];
    w2b[nt] = W2[(nt*16 + l15)*2 + 1];
    bia[nt] = b1[nt*16 + l15];
  }
  const float bb0 = b2[0], bb1 = b2[1];

  const int wid = (blockIdx.x*256 + threadIdx.x) >> 6;
  const int nw  = gridDim.x*4;
  const int nT  = (E + 15) >> 4;

  for (int t = wid; t < nT; t += nw) {
    const int tb = t*16;
    int e = tb + l15; if (e >= E) e = E - 1;
    const int s = src[e], d = dst[e];

    bf16x8 a0 = *(const bf16x8*)(h3b + (size_t)s*64 + quad*8);
    bf16x8 a1 = *(const bf16x8*)(h3b + (size_t)s*64 + 32 + quad*8);
    bf16x8 a2 = *(const bf16x8*)(h3b + (size_t)d*64 + quad*8);
    bf16x8 a3 = *(const bf16x8*)(h3b + (size_t)d*64 + 32 + quad*8);
    bf16x8 a4 = {};
    if (quad < 2) {
      const float4* ap = (const float4*)(attr + (size_t)e*16 + quad*8);
      float4 f0 = ap[0], f1 = ap[1];
      a4[0] = (short)f2bf(f0.x); a4[1] = (short)f2bf(f0.y);
      a4[2] = (short)f2bf(f0.z); a4[3] = (short)f2bf(f0.w);
      a4[4] = (short)f2bf(f1.x); a4[5] = (short)f2bf(f1.y);
      a4[6] = (short)f2bf(f1.z); a4[7] = (short)f2bf(f1.w);
    }

    f32x4 acc[8];
    #pragma unroll
    for (int nt = 0; nt < 8; ++nt) acc[nt] = (f32x4){0.f,0.f,0.f,0.f};

    #pragma unroll
    for (int nt = 0; nt < 8; ++nt) {
      acc[nt] = __builtin_amdgcn_mfma_f32_16x16x32_bf16(a0, Bf[(nt*5+0)*64 + lane], acc[nt], 0,0,0);
      acc[nt] = __builtin_amdgcn_mfma_f32_16x16x32_bf16(a1, Bf[(nt*5+1)*64 + lane], acc[nt], 0,0,0);
      acc[nt] = __builtin_amdgcn_mfma_f32_16x16x32_bf16(a2, Bf[(nt*5+2)*64 + lane], acc[nt], 0,0,0);
      acc[nt] = __builtin_amdgcn_mfma_f32_16x16x32_bf16(a3, Bf[(nt*5+3)*64 + lane], acc[nt], 0,0,0);
      acc[nt] = __builtin_amdgcn_mfma_f32_16x16x32_bf16(a4, Bf[(nt*5+4)*64 + lane], acc[nt], 0,0,0);
    }

    #pragma unroll
    for (int r = 0; r < 4; ++r) {
      float p0 = 0.f, p1 = 0.f;
      #pragma unroll
      for (int nt = 0; nt < 8; ++nt) {
        float hv = fmaxf(acc[nt][r] + bia[nt], 0.f);
        p0 = fmaf(hv, w2a[nt], p0);
        p1 = fmaf(hv, w2b[nt], p1);
      }
      #pragma unroll
      for (int off = 1; off < 16; off <<= 1) {
        p0 += __shfl_xor(p0, off, 64);
        p1 += __shfl_xor(p1, off, 64);
      }
      if (l15 == 0) {
        int eo = tb + quad*4 + r;
        if (eo < E) {
          p0 += bb0; p1 += bb1;
          float mm = fmaxf(p0, p1);
          float ls = mm + __logf(__expf(p0-mm) + __expf(p1-mm));
          ((float2*)out)[eo] = make_float2(p0 - ls, p1 - ls);
        }
      }
    }
  }
}

extern "C" void kernel_launch(void* const* d_in, const int* in_sizes, int n_in,
                              void* d_out, int out_size, void* d_ws, size_t ws_size,
                              hipStream_t stream) {
  const float* x      = (const float*)d_in[0];
  const int*   ei     = (const int*)d_in[1];
  const float* attr   = (const float*)d_in[2];
  const float* W1     = (const float*)d_in[3];
  const float* a_src1 = (const float*)d_in[4];
  const float* a_dst1 = (const float*)d_in[5];
  const float* b1     = (const float*)d_in[6];
  const float* W2     = (const float*)d_in[7];
  const float* a_src2 = (const float*)d_in[8];
  const float* a_dst2 = (const float*)d_in[9];
  const float* b2     = (const float*)d_in[10];
  const float* linW   = (const float*)d_in[11];
  const float* linb   = (const float*)d_in[12];
  const float* mW1    = (const float*)d_in[13];
  const float* mb1    = (const float*)d_in[14];
  const float* mW2    = (const float*)d_in[15];
  const float* mb2    = (const float*)d_in[16];
  float* out = (float*)d_out;

  int N = in_sizes[0] / 128;
  int E = in_sizes[1] / 2;
  const int* src = ei;
  const int* dst = ei + E;

  char* ws = (char*)d_ws;
  float*    bufH   = (float*)(ws);                 // 25.6 MB fp32: h1 / h2
  ushort*   bufAb  = (ushort*)(ws + 25600000);     // 12.8 MB bf16: xW1 / xW2
  ushort*   h3b    = (ushort*)(ws + 38400000);     // 12.8 MB bf16: h3
  int*      csr    = (int*)  (ws + 51200000);      // 6.4 MB
  float*    alS    = (float*)(ws + 57600000);      // 3.2 MB (layer1: N*8, layer2: N)
  float*    alD    = (float*)(ws + 60800000);      // 3.2 MB
  int*      rowptr = (int*)  (ws + 64000000);
  int*      degcur = (int*)  (ws + 64400064);
  int*      part   = (int*)  (ws + 64800064);
  ushort*   w1sw   = (ushort*)(ws + 64900096);     // 40 KB

  int gN4 = (N + 3) / 4;
  int gE  = (E + 255) / 256;
  int nChunk = (N + 1023) / 1024;

  // ---- CSR build ----
  hipMemsetAsync(degcur, 0, (size_t)N*sizeof(int), stream);
  hist_kernel<<<gE, 256, 0, stream>>>(dst, degcur, E);
  scan_p1<<<nChunk, 256, 0, stream>>>(degcur, part, N);
  scan_p2<<<1, 128, 0, stream>>>(part, rowptr, nChunk, N);
  scan_p3<<<nChunk, 256, 0, stream>>>(degcur, part, rowptr, degcur, N);
  scatter_kernel<<<gE, 256, 0, stream>>>(src, dst, degcur, csr, E);
  w1_swizzle<<<10, 256, 0, stream>>>(mW1, w1sw);

  // ---- layer 1 (gemm + fused logits) ----
  gemm_n64<<<gN4, 256, 0, stream>>>(x, W1, nullptr, bufAb, N, 128, 1, a_src1, a_dst1, alS, alD);
  agg1<<<gN4, 256, 0, stream>>>(bufAb, alS, alD, rowptr, csr, b1, bufH, N);
  // ---- layer 2 ----
  gemm_n64<<<gN4, 256, 0, stream>>>(bufH, W2, nullptr, bufAb, N, 64, 2, a_src2, a_dst2, alS, alD);
  agg2<<<gN4, 256, 0, stream>>>(bufAb, alS, alD, rowptr, csr, b2, bufH, N);
  // ---- linear -> h3 bf16 ----
  gemm_n64<<<gN4, 256, 0, stream>>>(bufH, linW, linb, h3b, N, 64, 0, nullptr, nullptr, nullptr, nullptr);
  // ---- fused edge MLP ----
  edge_mlp_mfma<<<2048, 256, 0, stream>>>(h3b, attr, src, dst, w1sw, mb1, mW2, mb2, out, E);
}

// Round 7
// 1144.397 us; speedup vs baseline: 1.3191x; 1.0076x over previous
//
#include <hip/hip_runtime.h>
#include <math.h>

#define DEV_INLINE __device__ __forceinline__
typedef unsigned short ushort;
typedef __attribute__((ext_vector_type(8))) short bf16x8;
typedef __attribute__((ext_vector_type(4))) float f32x4;

DEV_INLINE float lrelu(float x){ return x > 0.f ? x : 0.2f*x; }
DEV_INLINE float eluf(float x){ return x>0.f? x : (__expf(x)-1.f); }
DEV_INLINE ushort f2bf(float f){
  unsigned u = __float_as_uint(f);
  return (ushort)((u + 0x7FFFu + ((u>>16)&1u)) >> 16);   // RNE
}
DEV_INLINE float b2f(ushort u){ return __uint_as_float(((unsigned)u)<<16); }

// ---------------- node GEMM: Cb[n][64] = bf16(A[n][K] @ W[K][64] (+bias)) ----------------
// mode 1: also emit 8-head logits (alS/alD [n][8]); mode 2: 1-head logits [n]
__global__ __launch_bounds__(256) void gemm_n64(const float* __restrict__ A, const float* __restrict__ W,
    const float* __restrict__ bias, ushort* __restrict__ Cb, int n, int K,
    int mode, const float* __restrict__ asrc, const float* __restrict__ adst,
    float* __restrict__ alS, float* __restrict__ alD)
{
  int j = threadIdx.x & 63;
  int node = blockIdx.x*4 + (threadIdx.x>>6);
  if (node >= n) return;   // wave-uniform (one node per wave)
  const float4* A4 = (const float4*)(A + (size_t)node*K);
  float acc = 0.f;
  int K4 = K>>2;
  for (int k4 = 0; k4 < K4; ++k4) {
    float4 a = A4[k4];
    const float* w = W + k4*256 + j;
    acc = fmaf(a.x, w[0],   acc);
    acc = fmaf(a.y, w[64],  acc);
    acc = fmaf(a.z, w[128], acc);
    acc = fmaf(a.w, w[192], acc);
  }
  if (bias) acc += bias[j];
  Cb[(size_t)node*64 + j] = f2bf(acc);
  if (mode == 1) {
    float s = acc * asrc[j];
    float d = acc * adst[j];
    #pragma unroll
    for (int off = 1; off < 8; off <<= 1) { s += __shfl_xor(s, off, 64); d += __shfl_xor(d, off, 64); }
    if ((j & 7) == 0) {
      alS[(size_t)node*8 + (j>>3)] = s;
      alD[(size_t)node*8 + (j>>3)] = d;
    }
  } else if (mode == 2) {
    float s = acc * asrc[j];
    float d = acc * adst[j];
    #pragma unroll
    for (int off = 1; off < 64; off <<= 1) { s += __shfl_xor(s, off, 64); d += __shfl_xor(d, off, 64); }
    if (j == 0) { alS[node] = s; alD[node] = d; }
  }
}

// ---------------- CSR build (grouped by dst) ----------------
__global__ __launch_bounds__(256) void hist_kernel(const int* __restrict__ dst, int* __restrict__ deg, int E)
{
  int e = blockIdx.x*blockDim.x + threadIdx.x;
  if (e < E) atomicAdd(deg + dst[e], 1);
}

__global__ __launch_bounds__(256) void scan_p1(const int* __restrict__ deg, int* __restrict__ part, int n)
{
  __shared__ int red[256];
  int base = blockIdx.x*1024;
  int s = 0;
  for (int k = threadIdx.x; k < 1024; k += 256) { int i = base+k; s += (i<n)? deg[i] : 0; }
  red[threadIdx.x] = s; __syncthreads();
  for (int off = 128; off > 0; off >>= 1) {
    if (threadIdx.x < off) red[threadIdx.x] += red[threadIdx.x+off];
    __syncthreads();
  }
  if (threadIdx.x == 0) part[blockIdx.x] = red[0];
}

// parallel exclusive scan of nb (<=128) block partials
__global__ __launch_bounds__(128) void scan_p2(int* part, int* rowptr, int nb, int n)
{
  __shared__ int ts[128];
  int tid = threadIdx.x;
  int v = (tid < nb) ? part[tid] : 0;
  ts[tid] = v; __syncthreads();
  #pragma unroll
  for (int off = 1; off < 128; off <<= 1) {
    int t = (tid >= off) ? ts[tid-off] : 0;
    __syncthreads();
    ts[tid] += t;
    __syncthreads();
  }
  if (tid < nb) part[tid] = ts[tid] - v;   // exclusive
  if (tid == 127) rowptr[n] = ts[127];     // total
}

__global__ __launch_bounds__(256) void scan_p3(const int* __restrict__ deg, const int* __restrict__ part,
    int* __restrict__ rowptr, int* __restrict__ cursor, int n)
{
  __shared__ int ts[256];
  int tid = threadIdx.x;
  int base = blockIdx.x*1024 + tid*4;
  int v0=0,v1=0,v2=0,v3=0;
  if (base+0 < n) v0 = deg[base+0];
  if (base+1 < n) v1 = deg[base+1];
  if (base+2 < n) v2 = deg[base+2];
  if (base+3 < n) v3 = deg[base+3];
  ts[tid] = v0+v1+v2+v3; __syncthreads();
  for (int off = 1; off < 256; off <<= 1) {
    int t = (tid >= off) ? ts[tid-off] : 0;
    __syncthreads();
    ts[tid] += t;
    __syncthreads();
  }
  int ex = part[blockIdx.x] + (tid ? ts[tid-1] : 0);
  if (base+0 < n) { rowptr[base+0] = ex; cursor[base+0] = ex; ex += v0; }
  if (base+1 < n) { rowptr[base+1] = ex; cursor[base+1] = ex; ex += v1; }
  if (base+2 < n) { rowptr[base+2] = ex; cursor[base+2] = ex; ex += v2; }
  if (base+3 < n) { rowptr[base+3] = ex; cursor[base+3] = ex; ex += v3; }
}

__global__ __launch_bounds__(256) void scatter_kernel(const int* __restrict__ src, const int* __restrict__ dst,
    int* __restrict__ cursor, int* __restrict__ csr, int E)
{
  int e = blockIdx.x*blockDim.x + threadIdx.x;
  if (e >= E) return;
  int pos = atomicAdd(cursor + dst[e], 1);
  csr[pos] = src[e];
}

// ---------------- per-node gather aggregation, fixed-reference softmax ----------------
// w = exp(e - e_self): mathematically identical to max-subtracted softmax (ratio is
// reference-invariant); logits here are O(1) so exp cannot overflow. No loop-carried
// max/rescale chain -> fully pipelineable.
__global__ __launch_bounds__(256) void agg1(const ushort* __restrict__ xWb, const float* __restrict__ alS,
    const float* __restrict__ alD, const int* __restrict__ rowptr, const int* __restrict__ csr,
    const float* __restrict__ b, float* __restrict__ outp, int n)
{
  int node = blockIdx.x*4 + (threadIdx.x>>6);
  if (node >= n) return;
  int l = threadIdx.x & 63, h = l >> 3;
  float aD = alD[(size_t)node*8 + h];
  float r  = lrelu(alS[(size_t)node*8 + h] + aD);   // self-loop logit = reference
  float den = 1.f;
  float acc = b2f(xWb[(size_t)node*64 + l]);
  int p = rowptr[node], p1 = rowptr[node+1];
  for (; p+3 < p1; p += 4) {
    int s0 = csr[p], s1 = csr[p+1], s2 = csr[p+2], s3 = csr[p+3];
    float w0 = __expf(lrelu(alS[(size_t)s0*8 + h] + aD) - r);
    float w1 = __expf(lrelu(alS[(size_t)s1*8 + h] + aD) - r);
    float w2 = __expf(lrelu(alS[(size_t)s2*8 + h] + aD) - r);
    float w3 = __expf(lrelu(alS[(size_t)s3*8 + h] + aD) - r);
    float x0 = b2f(xWb[(size_t)s0*64 + l]);
    float x1 = b2f(xWb[(size_t)s1*64 + l]);
    float x2 = b2f(xWb[(size_t)s2*64 + l]);
    float x3 = b2f(xWb[(size_t)s3*64 + l]);
    den += (w0 + w1) + (w2 + w3);
    acc += (w0*x0 + w1*x1) + (w2*x2 + w3*x3);
  }
  for (; p < p1; ++p) {
    int s0 = csr[p];
    float w0 = __expf(lrelu(alS[(size_t)s0*8 + h] + aD) - r);
    acc += w0 * b2f(xWb[(size_t)s0*64 + l]);
    den += w0;
  }
  outp[(size_t)node*64 + l] = eluf(acc/(den + 1e-16f) + b[l]);
}

__global__ __launch_bounds__(256) void agg2(const ushort* __restrict__ xWb, const float* __restrict__ alS,
    const float* __restrict__ alD, const int* __restrict__ rowptr, const int* __restrict__ csr,
    const float* __restrict__ b, float* __restrict__ outp, int n)
{
  int node = blockIdx.x*4 + (threadIdx.x>>6);
  if (node >= n) return;
  int l = threadIdx.x & 63;
  float aD = alD[node];
  float r  = lrelu(alS[node] + aD);
  float den = 1.f;
  float acc = b2f(xWb[(size_t)node*64 + l]);
  int p = rowptr[node], p1 = rowptr[node+1];
  for (; p+3 < p1; p += 4) {
    int s0 = csr[p], s1 = csr[p+1], s2 = csr[p+2], s3 = csr[p+3];
    float w0 = __expf(lrelu(alS[s0] + aD) - r);
    float w1 = __expf(lrelu(alS[s1] + aD) - r);
    float w2 = __expf(lrelu(alS[s2] + aD) - r);
    float w3 = __expf(lrelu(alS[s3] + aD) - r);
    float x0 = b2f(xWb[(size_t)s0*64 + l]);
    float x1 = b2f(xWb[(size_t)s1*64 + l]);
    float x2 = b2f(xWb[(size_t)s2*64 + l]);
    float x3 = b2f(xWb[(size_t)s3*64 + l]);
    den += (w0 + w1) + (w2 + w3);
    acc += (w0*x0 + w1*x1) + (w2*x2 + w3*x3);
  }
  for (; p < p1; ++p) {
    int s0 = csr[p];
    float w0 = __expf(lrelu(alS[s0] + aD) - r);
    acc += w0 * b2f(xWb[(size_t)s0*64 + l]);
    den += w0;
  }
  outp[(size_t)node*64 + l] = eluf(acc/(den + 1e-16f) + b[l]);
}

// W1[144][128] fp32 -> B-fragment-ordered bf16 image: [8 ntile][5 kstep][64 lane][8 bf16]
__global__ void w1_swizzle(const float* __restrict__ W1, ushort* __restrict__ w1sw)
{
  int t = blockIdx.x*blockDim.x + threadIdx.x;
  if (t >= 2560) return;
  int l = t & 63, nk = t >> 6;
  int nt = nk/5, ks = nk - nt*5;
  int ncol = nt*16 + (l&15);
  int kb = ks*32 + (l>>4)*8;
  union { ushort u[8]; uint4 q; } v;
  #pragma unroll
  for (int j = 0; j < 8; ++j) {
    int k = kb + j;
    float f = (k < 144) ? W1[k*128 + ncol] : 0.f;
    v.u[j] = f2bf(f);
  }
  ((uint4*)w1sw)[t] = v.q;
}

// ---------------- edge MLP via MFMA: wave per 16-edge tile ----------------
// LDS kept at 32 KB (k-steps 0-3 only; k-step 4 B-frags live in registers):
// at 40 KB LDS only 1 block/CU was resident (Occupancy ~11% at both grid 1024
// and 2048 in R5/R6) — concurrent-LDS scheduling window appears to be 64 KB.
// Natural VGPR (no min-waves bound): R4's forced VGPR=64 spilled accumulators
// (WRITE 12.5->264 MB, 2.2x slower).
__global__ __launch_bounds__(256) void edge_mlp_mfma(
    const ushort* __restrict__ h3b, const float* __restrict__ attr,
    const int* __restrict__ src, const int* __restrict__ dst,
    const ushort* __restrict__ w1sw, const float* __restrict__ b1,
    const float* __restrict__ W2, const float* __restrict__ b2,
    float* __restrict__ out, int E)
{
  __shared__ uint4 W1s[2048];            // 32 KB: 8 ntile x 4 kstep x 64 lane
  for (int i = threadIdx.x; i < 2048; i += 256) {
    int fi = i >> 6, l = i & 63;
    int nt = fi >> 2, ks = fi & 3;
    W1s[i] = ((const uint4*)w1sw)[(nt*5 + ks)*64 + l];
  }
  __syncthreads();
  const bf16x8* Bf = (const bf16x8*)W1s;

  const int lane = threadIdx.x & 63;
  const int quad = lane >> 4, l15 = lane & 15;

  // k-step 4 (attr rows) B-fragments: loop-invariant, in registers
  bf16x8 b4[8];
  #pragma unroll
  for (int nt = 0; nt < 8; ++nt)
    b4[nt] = *(const bf16x8*)(w1sw + ((size_t)(nt*5 + 4)*64 + lane)*8);

  float w2a[8], w2b[8], bia[8];
  #pragma unroll
  for (int nt = 0; nt < 8; ++nt) {
    w2a[nt] = W2[(nt*16 + l15)*2 + 0];
    w2b[nt] = W2[(nt*16 + l15)*2 + 1];
    bia[nt] = b1[nt*16 + l15];
  }
  const float bb0 = b2[0], bb1 = b2[1];

  const int wid = (blockIdx.x*256 + threadIdx.x) >> 6;
  const int nw  = gridDim.x*4;
  const int nT  = (E + 15) >> 4;

  for (int t = wid; t < nT; t += nw) {
    const int tb = t*16;
    int e = tb + l15; if (e >= E) e = E - 1;
    const int s = src[e], d = dst[e];

    bf16x8 a0 = *(const bf16x8*)(h3b + (size_t)s*64 + quad*8);
    bf16x8 a1 = *(const bf16x8*)(h3b + (size_t)s*64 + 32 + quad*8);
    bf16x8 a2 = *(const bf16x8*)(h3b + (size_t)d*64 + quad*8);
    bf16x8 a3 = *(const bf16x8*)(h3b + (size_t)d*64 + 32 + quad*8);
    bf16x8 a4 = {};
    if (quad < 2) {
      const float4* ap = (const float4*)(attr + (size_t)e*16 + quad*8);
      float4 f0 = ap[0], f1 = ap[1];
      a4[0] = (short)f2bf(f0.x); a4[1] = (short)f2bf(f0.y);
      a4[2] = (short)f2bf(f0.z); a4[3] = (short)f2bf(f0.w);
      a4[4] = (short)f2bf(f1.x); a4[5] = (short)f2bf(f1.y);
      a4[6] = (short)f2bf(f1.z); a4[7] = (short)f2bf(f1.w);
    }

    f32x4 acc[8];
    #pragma unroll
    for (int nt = 0; nt < 8; ++nt) acc[nt] = (f32x4){0.f,0.f,0.f,0.f};

    #pragma unroll
    for (int nt = 0; nt < 8; ++nt) {
      acc[nt] = __builtin_amdgcn_mfma_f32_16x16x32_bf16(a0, Bf[(nt*4+0)*64 + lane], acc[nt], 0,0,0);
      acc[nt] = __builtin_amdgcn_mfma_f32_16x16x32_bf16(a1, Bf[(nt*4+1)*64 + lane], acc[nt], 0,0,0);
      acc[nt] = __builtin_amdgcn_mfma_f32_16x16x32_bf16(a2, Bf[(nt*4+2)*64 + lane], acc[nt], 0,0,0);
      acc[nt] = __builtin_amdgcn_mfma_f32_16x16x32_bf16(a3, Bf[(nt*4+3)*64 + lane], acc[nt], 0,0,0);
      acc[nt] = __builtin_amdgcn_mfma_f32_16x16x32_bf16(a4, b4[nt], acc[nt], 0,0,0);
    }

    #pragma unroll
    for (int r = 0; r < 4; ++r) {
      float p0 = 0.f, p1 = 0.f;
      #pragma unroll
      for (int nt = 0; nt < 8; ++nt) {
        float hv = fmaxf(acc[nt][r] + bia[nt], 0.f);
        p0 = fmaf(hv, w2a[nt], p0);
        p1 = fmaf(hv, w2b[nt], p1);
      }
      #pragma unroll
      for (int off = 1; off < 16; off <<= 1) {
        p0 += __shfl_xor(p0, off, 64);
        p1 += __shfl_xor(p1, off, 64);
      }
      if (l15 == 0) {
        int eo = tb + quad*4 + r;
        if (eo < E) {
          p0 += bb0; p1 += bb1;
          float mm = fmaxf(p0, p1);
          float ls = mm + __logf(__expf(p0-mm) + __expf(p1-mm));
          ((float2*)out)[eo] = make_float2(p0 - ls, p1 - ls);
        }
      }
    }
  }
}

extern "C" void kernel_launch(void* const* d_in, const int* in_sizes, int n_in,
                              void* d_out, int out_size, void* d_ws, size_t ws_size,
                              hipStream_t stream) {
  const float* x      = (const float*)d_in[0];
  const int*   ei     = (const int*)d_in[1];
  const float* attr   = (const float*)d_in[2];
  const float* W1     = (const float*)d_in[3];
  const float* a_src1 = (const float*)d_in[4];
  const float* a_dst1 = (const float*)d_in[5];
  const float* b1     = (const float*)d_in[6];
  const float* W2     = (const float*)d_in[7];
  const float* a_src2 = (const float*)d_in[8];
  const float* a_dst2 = (const float*)d_in[9];
  const float* b2     = (const float*)d_in[10];
  const float* linW   = (const float*)d_in[11];
  const float* linb   = (const float*)d_in[12];
  const float* mW1    = (const float*)d_in[13];
  const float* mb1    = (const float*)d_in[14];
  const float* mW2    = (const float*)d_in[15];
  const float* mb2    = (const float*)d_in[16];
  float* out = (float*)d_out;

  int N = in_sizes[0] / 128;
  int E = in_sizes[1] / 2;
  const int* src = ei;
  const int* dst = ei + E;

  char* ws = (char*)d_ws;
  float*    bufH   = (float*)(ws);                 // 25.6 MB fp32: h1 / h2
  ushort*   bufAb  = (ushort*)(ws + 25600000);     // 12.8 MB bf16: xW1 / xW2
  ushort*   h3b    = (ushort*)(ws + 38400000);     // 12.8 MB bf16: h3
  int*      csr    = (int*)  (ws + 51200000);      // 6.4 MB
  float*    alS    = (float*)(ws + 57600000);      // 3.2 MB (layer1: N*8, layer2: N)
  float*    alD    = (float*)(ws + 60800000);      // 3.2 MB
  int*      rowptr = (int*)  (ws + 64000000);
  int*      degcur = (int*)  (ws + 64400064);
  int*      part   = (int*)  (ws + 64800064);
  ushort*   w1sw   = (ushort*)(ws + 64900096);     // 40 KB

  int gN4 = (N + 3) / 4;
  int gE  = (E + 255) / 256;
  int nChunk = (N + 1023) / 1024;

  // ---- CSR build ----
  hipMemsetAsync(degcur, 0, (size_t)N*sizeof(int), stream);
  hist_kernel<<<gE, 256, 0, stream>>>(dst, degcur, E);
  scan_p1<<<nChunk, 256, 0, stream>>>(degcur, part, N);
  scan_p2<<<1, 128, 0, stream>>>(part, rowptr, nChunk, N);
  scan_p3<<<nChunk, 256, 0, stream>>>(degcur, part, rowptr, degcur, N);
  scatter_kernel<<<gE, 256, 0, stream>>>(src, dst, degcur, csr, E);
  w1_swizzle<<<10, 256, 0, stream>>>(mW1, w1sw);

  // ---- layer 1 (gemm + fused logits) ----
  gemm_n64<<<gN4, 256, 0, stream>>>(x, W1, nullptr, bufAb, N, 128, 1, a_src1, a_dst1, alS, alD);
  agg1<<<gN4, 256, 0, stream>>>(bufAb, alS, alD, rowptr, csr, b1, bufH, N);
  // ---- layer 2 ----
  gemm_n64<<<gN4, 256, 0, stream>>>(bufH, W2, nullptr, bufAb, N, 64, 2, a_src2, a_dst2, alS, alD);
  agg2<<<gN4, 256, 0, stream>>>(bufAb, alS, alD, rowptr, csr, b2, bufH, N);
  // ---- linear -> h3 bf16 ----
  gemm_n64<<<gN4, 256, 0, stream>>>(bufH, linW, linb, h3b, N, 64, 0, nullptr, nullptr, nullptr, nullptr);
  // ---- fused edge MLP ----
  edge_mlp_mfma<<<2048, 256, 0, stream>>>(h3b, attr, src, dst, w1sw, mb1, mW2, mb2, out, E);
}